// Round 7
// baseline (322.383 us; speedup 1.0000x reference)
//
#include <hip/hip_runtime.h>
#include <cstdint>
#include <climits>

// Binarized 4-layer MLP via exact int8 MFMA (i32 accum) on gfx950.
// Layers 1-3: BN+hardtanh+sign folds to an exact integer threshold on the
// i32 dot; layer 4 is affine. Round-7: 8-phase-class schedule for the big
// GEMMs — 256^2 tile, tri-buffered LDS (96 KB), loads issued 2 K-tiles
// ahead, steady-state vmcnt(8) (never drained mid-loop), per-tile 3
// sub-phases {ds_read 6/4/2 -> barrier -> setprio(1) -> 8/8/16 MFMA}.

typedef __attribute__((ext_vector_type(4))) int i32x4_t;

__device__ __forceinline__ void gload_lds16(const void* g, void* l) {
  __builtin_amdgcn_global_load_lds(
      (const __attribute__((address_space(1))) unsigned int*)g,
      (__attribute__((address_space(3))) unsigned int*)l, 16, 0, 0);
}

__device__ __forceinline__ int pack4(const float4 v) {
  int b0 = v.x > 0.f ? 1 : (v.x < 0.f ? -1 : 0);
  int b1 = v.y > 0.f ? 1 : (v.y < 0.f ? -1 : 0);
  int b2 = v.z > 0.f ? 1 : (v.z < 0.f ? -1 : 0);
  int b3 = v.w > 0.f ? 1 : (v.w < 0.f ? -1 : 0);
  return (b0 & 0xff) | ((b1 & 0xff) << 8) | ((b2 & 0xff) << 16) | (b3 << 24);
}

// ============================ FAST PATH (i8 MFMA) ===========================

// One dispatch does all conversions + threshold prep:
//   blocks [0, 32768):        x rows -> i8 A0 (stride 832, pad zeroed)
//   blocks [32768, 35968):    W1..W4 -> i8 (W1 stride 832)
//   blocks [35968, 35981):    integer thresholds (f64) + final affine params
__global__ __launch_bounds__(256) void prep_mega_kernel(
    const float* __restrict__ x, int8_t* __restrict__ A0,
    const float* __restrict__ W1f, const float* __restrict__ W2f,
    const float* __restrict__ W3f, const float* __restrict__ W4f,
    int8_t* __restrict__ Wp1, int8_t* __restrict__ Wp2,
    int8_t* __restrict__ Wp3, int8_t* __restrict__ Wp4,
    const float* b1, const float* g1, const float* be1, const float* m1, const float* v1,
    const float* b2, const float* g2, const float* be2, const float* m2, const float* v2,
    const float* b3, const float* g3, const float* be3, const float* m3, const float* v3,
    const float* b4, const float* g4, const float* be4, const float* m4, const float* v4,
    int* __restrict__ T1, int* __restrict__ T2, int* __restrict__ T3,
    int8_t* __restrict__ S1, int8_t* __restrict__ S2, int8_t* __restrict__ S3,
    float* __restrict__ sc4, float* __restrict__ of4) {
  const int b = blockIdx.x;
  const int t = threadIdx.x;
  if (b < 32768) {
    const int col = t * 4;
    if (col < 784) {
      int packed = pack4(*(const float4*)(x + (size_t)b * 784 + col));
      *(int*)(A0 + (size_t)b * 832 + col) = packed;
    } else if (col < 832) {
      *(int*)(A0 + (size_t)b * 832 + col) = 0;  // zero the K-pad
    }
  } else if (b < 35968) {
    const int b2i = b - 32768;
    const float* Wf; int8_t* Wp; int N, K, n, ost;
    if (b2i < 1024)      { Wf = W1f; Wp = Wp1; N = 1024; K = 784;  n = b2i;        ost = 832;  }
    else if (b2i < 2048) { Wf = W2f; Wp = Wp2; N = 1024; K = 1024; n = b2i - 1024; ost = 1024; }
    else if (b2i < 3072) { Wf = W3f; Wp = Wp3; N = 1024; K = 1024; n = b2i - 2048; ost = 1024; }
    else                 { Wf = W4f; Wp = Wp4; N = 10;   K = 1024; n = b2i - 3072; ost = 1024; }
    const int col = t * 4;
    if (col < ost) {
      int packed = 0;
      if (n < N && col + 3 < K)
        packed = pack4(*(const float4*)(Wf + (size_t)n * K + col));
      *(int*)(Wp + (size_t)n * ost + col) = packed;
    }
  } else {
    const int pb = b - 35968;
    if (pb < 12) {
      const int layer = pb >> 2;
      const int n = (pb & 3) * 256 + t;
      const float *bb, *gg, *be, *me, *va; int* T; int8_t* S;
      if (layer == 0)      { bb = b1; gg = g1; be = be1; me = m1; va = v1; T = T1; S = S1; }
      else if (layer == 1) { bb = b2; gg = g2; be = be2; me = m2; va = v2; T = T2; S = S2; }
      else                 { bb = b3; gg = g3; be = be3; me = m3; va = v3; T = T3; S = S3; }
      double g = (double)gg[n];
      double rs = 1.0 / sqrt((double)va[n] + 1e-5);
      int th; int8_t s;
      if (g > 0.0) {
        double tv = (double)me[n] - (double)bb[n] - (double)be[n] / (g * rs);
        tv = fmin(fmax(tv, -2.0e9), 2.0e9);
        th = (int)floor(tv) + 1; s = 1;
      } else if (g < 0.0) {
        double tv = (double)me[n] - (double)bb[n] - (double)be[n] / (g * rs);
        tv = fmin(fmax(tv, -2.0e9), 2.0e9);
        th = (int)ceil(tv); s = -1;
      } else {
        th = INT_MIN; s = (be[n] > 0.f) ? (int8_t)1 : (int8_t)-1;
      }
      T[n] = th; S[n] = s;
    } else if (t < 10) {
      double rs = 1.0 / sqrt((double)v4[t] + 1e-5);
      double sd = (double)g4[t] * rs;
      sc4[t] = (float)sd;
      of4[t] = (float)(sd * ((double)b4[t] - (double)m4[t]) + (double)be4[t]);
    }
  }
}

// 256x256 tile, BK=64, 512 threads = 8 waves (2M x 4N), wave tile 128x64 =
// 8x4 frags of mfma_i32_16x16x64_i8. Tri-buffered LDS (3 x 32 KiB): while
// computing tile t, tiles t+1 and t+2 are in flight (4 gload_lds/thread/tile
// issued at iteration start). vmcnt(8) retires exactly tile t's 4 loads.
// Per tile 3 sub-phases: {ds_read 6 -> bar -> prio1 -> 8 MFMA}, {ds_read 4
// -> bar -> 8 MFMA}, {ds_read 2 -> bar -> 16 MFMA}. Writes at iter t+1 hit
// buf[t%3] whose reads all precede P2's barrier at iter t -> no end barrier.
// 16B-slot XOR swizzle via pre-swizzled global source; bijective XCD swizzle.
__global__ __launch_bounds__(512, 2) void gemm_bnn256p_kernel(
    const int8_t* __restrict__ A, const int8_t* __restrict__ W,
    int ldk, int nkt,
    const int* __restrict__ T, const int8_t* __restrict__ S,
    int8_t* __restrict__ Aout) {
  __shared__ i32x4_t smem[6144];  // 96 KiB: 3 bufs x (A 16K + B 16K)
  int8_t* sm = (int8_t*)smem;
  const int tid = threadIdx.x;
  const int lane = tid & 63;
  const int w = tid >> 6;          // 0..7
  const int wm = w >> 2, wn = w & 3;

  // XCD swizzle: 512 blocks = 8 XCDs x 64; same-stripe col-blocks contiguous
  const int bid = blockIdx.x;
  const int swz = (bid & 7) * 64 + (bid >> 3);
  const int row0 = (swz >> 2) * 256;   // 128 row stripes
  const int col0 = (swz & 3) * 256;    // 4 col blocks

  // staging: 4 jobs/thread/K-tile (A-half0, A-half1, B-half0, B-half1),
  // each 16B. granule j in [0,1024): row=j>>2, slot=(j&3)^((row>>1)&3).
  const int8_t* gsrc[4];
  int gdst[4];
#pragma unroll
  for (int h = 0; h < 4; ++h) {
    const int j = (h & 1) * 512 + tid;
    const int r = j >> 2;
    const int s = (j & 3) ^ ((r >> 1) & 3);
    gsrc[h] = ((h >= 2) ? (W + (size_t)(col0 + r) * ldk)
                        : (A + (size_t)(row0 + r) * ldk)) + s * 16;
    gdst[h] = ((h >= 2) ? 16384 : 0) + j * 16;
  }

  // per-lane LDS read byte offsets (within one buffer)
  int a_off[8], b_off[4];
#pragma unroll
  for (int m = 0; m < 8; ++m) {
    int ra = wm * 128 + m * 16 + (lane & 15);
    a_off[m] = ra * 64 + ((((lane >> 4) ^ (ra >> 1)) & 3) << 4);
  }
#pragma unroll
  for (int n = 0; n < 4; ++n) {
    int rb = wn * 64 + n * 16 + (lane & 15);
    b_off[n] = 16384 + rb * 64 + ((((lane >> 4) ^ (rb >> 1)) & 3) << 4);
  }

  i32x4_t acc[8][4];
#pragma unroll
  for (int m = 0; m < 8; ++m)
#pragma unroll
    for (int n = 0; n < 4; ++n) acc[m][n] = (i32x4_t){0, 0, 0, 0};

  // prologue: issue tiles 0 (buf0) and 1 (buf1) -> 8 loads/thread in flight
#pragma unroll
  for (int h = 0; h < 4; ++h) { gload_lds16(gsrc[h], sm + gdst[h]); gsrc[h] += 64; }
#pragma unroll
  for (int h = 0; h < 4; ++h) { gload_lds16(gsrc[h], sm + 32768 + gdst[h]); gsrc[h] += 64; }

  int bufr = 0;  // byte base of tile kt's buffer
  for (int kt = 0; kt < nkt; ++kt) {
    if (kt + 2 < nkt) {
      int bufw = bufr + 65536; if (bufw >= 98304) bufw -= 98304;
#pragma unroll
      for (int h = 0; h < 4; ++h) { gload_lds16(gsrc[h], sm + bufw + gdst[h]); gsrc[h] += 64; }
      // retire tile kt's 4 loads; tiles kt+1, kt+2 (8 loads) stay in flight
      asm volatile("s_waitcnt vmcnt(8)" ::: "memory");
    } else if (kt + 1 < nkt) {
      asm volatile("s_waitcnt vmcnt(4)" ::: "memory");
    } else {
      asm volatile("s_waitcnt vmcnt(0)" ::: "memory");
    }
    asm volatile("s_barrier" ::: "memory");  // tile kt's LDS writes visible

    const int8_t* const bb = sm + bufr;
    i32x4_t av[8], bv[4];

    // ---- P0: av0-3 + bv0-1 -> acc[0-3][0-1] ----
#pragma unroll
    for (int i = 0; i < 4; ++i) av[i] = *(const i32x4_t*)(bb + a_off[i]);
    bv[0] = *(const i32x4_t*)(bb + b_off[0]);
    bv[1] = *(const i32x4_t*)(bb + b_off[1]);
    asm volatile("s_barrier" ::: "memory");
    __builtin_amdgcn_s_setprio(1);
#pragma unroll
    for (int m = 0; m < 4; ++m)
#pragma unroll
      for (int n = 0; n < 2; ++n)
        acc[m][n] = __builtin_amdgcn_mfma_i32_16x16x64_i8(av[m], bv[n], acc[m][n], 0, 0, 0);
    __builtin_amdgcn_s_setprio(0);

    // ---- P1: av4-7 -> acc[4-7][0-1] ----
#pragma unroll
    for (int i = 0; i < 4; ++i) av[4 + i] = *(const i32x4_t*)(bb + a_off[4 + i]);
    asm volatile("s_barrier" ::: "memory");
    __builtin_amdgcn_s_setprio(1);
#pragma unroll
    for (int m = 0; m < 4; ++m)
#pragma unroll
      for (int n = 0; n < 2; ++n)
        acc[4 + m][n] = __builtin_amdgcn_mfma_i32_16x16x64_i8(av[4 + m], bv[n], acc[4 + m][n], 0, 0, 0);
    __builtin_amdgcn_s_setprio(0);

    // ---- P2: bv2-3 -> acc[0-7][2-3] (last reads of tile kt precede this
    //      barrier, so next iteration may overwrite buf[kt%3] safely) ----
    bv[2] = *(const i32x4_t*)(bb + b_off[2]);
    bv[3] = *(const i32x4_t*)(bb + b_off[3]);
    asm volatile("s_barrier" ::: "memory");
    __builtin_amdgcn_s_setprio(1);
#pragma unroll
    for (int m = 0; m < 8; ++m)
#pragma unroll
      for (int n = 2; n < 4; ++n)
        acc[m][n] = __builtin_amdgcn_mfma_i32_16x16x64_i8(av[m], bv[n], acc[m][n], 0, 0, 0);
    __builtin_amdgcn_s_setprio(0);

    bufr += 32768; if (bufr >= 98304) bufr = 0;
  }

  // epilogue: C/D layout col=lane&15, row=(lane>>4)*4+reg  [verified m89]
#pragma unroll
  for (int n = 0; n < 4; ++n) {
    const int oc = col0 + wn * 64 + n * 16 + (lane & 15);
    const int tn = T[oc];
    const int8_t sn = S[oc];
#pragma unroll
    for (int m = 0; m < 8; ++m) {
      const int orb = row0 + wm * 128 + m * 16 + ((lane >> 4) << 2);
#pragma unroll
      for (int r = 0; r < 4; ++r) {
        int8_t v = (acc[m][n][r] >= tn) ? sn : (int8_t)(-sn);
        Aout[(size_t)(orb + r) * 1024 + oc] = v;
      }
    }
  }
}

// Final layer: 128x128 tile (only cols 0..9 live), proven 2-phase structure.
__global__ __launch_bounds__(256) void gemm_final_kernel(
    const int8_t* __restrict__ A, const int8_t* __restrict__ W,
    int ldk, int nkt,
    const float* __restrict__ scale, const float* __restrict__ offs,
    float* __restrict__ out) {
  __shared__ i32x4_t smem[2048];  // 32 KiB
  int8_t* sm = (int8_t*)smem;
  const int tid = threadIdx.x;
  const int lane = tid & 63;
  const int w = tid >> 6;
  const int wrow = w >> 1, wcol = w & 1;
  const int row0 = blockIdx.x * 128;
  const int col0 = 0;

  const int jj0 = tid, jj1 = tid + 256;
  const int r0 = jj0 >> 2, r1 = jj1 >> 2;
  const int s0 = (jj0 & 3) ^ ((r0 >> 1) & 3);
  const int s1 = (jj1 & 3) ^ ((r1 >> 1) & 3);
  const int8_t* aS0 = A + (size_t)(row0 + r0) * ldk + s0 * 16;
  const int8_t* aS1 = A + (size_t)(row0 + r1) * ldk + s1 * 16;
  const int8_t* bS0 = W + (size_t)(col0 + r0) * ldk + s0 * 16;
  const int8_t* bS1 = W + (size_t)(col0 + r1) * ldk + s1 * 16;
  const int dA0 = jj0 * 16, dA1 = jj1 * 16;
  const int dB0 = 8192 + jj0 * 16, dB1 = 8192 + jj1 * 16;

  int a_off[4], b_off[4];
#pragma unroll
  for (int i = 0; i < 4; ++i) {
    int ra = wrow * 64 + i * 16 + (lane & 15);
    a_off[i] = ra * 64 + ((((lane >> 4) ^ (ra >> 1)) & 3) << 4);
    int rb = wcol * 64 + i * 16 + (lane & 15);
    b_off[i] = 8192 + rb * 64 + ((((lane >> 4) ^ (rb >> 1)) & 3) << 4);
  }

  i32x4_t acc[4][4];
#pragma unroll
  for (int m = 0; m < 4; ++m)
#pragma unroll
    for (int n = 0; n < 4; ++n) acc[m][n] = (i32x4_t){0, 0, 0, 0};

  gload_lds16(aS0, sm + dA0);
  gload_lds16(aS1, sm + dA1);
  gload_lds16(bS0, sm + dB0);
  gload_lds16(bS1, sm + dB1);

  for (int kt = 0; kt < nkt - 1; ++kt) {
    aS0 += 64; aS1 += 64; bS0 += 64; bS1 += 64;
    int8_t* smw = sm + (((kt + 1) & 1) << 14);
    gload_lds16(aS0, smw + dA0);
    gload_lds16(aS1, smw + dA1);
    gload_lds16(bS0, smw + dB0);
    gload_lds16(bS1, smw + dB1);
    asm volatile("s_waitcnt vmcnt(4)" ::: "memory");
    asm volatile("s_barrier" ::: "memory");
    const int8_t* smr = sm + ((kt & 1) << 14);
    i32x4_t av[4], bv[4];
#pragma unroll
    for (int i = 0; i < 4; ++i) av[i] = *(const i32x4_t*)(smr + a_off[i]);
#pragma unroll
    for (int i = 0; i < 4; ++i) bv[i] = *(const i32x4_t*)(smr + b_off[i]);
#pragma unroll
    for (int m = 0; m < 4; ++m)
#pragma unroll
      for (int n = 0; n < 4; ++n)
        acc[m][n] = __builtin_amdgcn_mfma_i32_16x16x64_i8(av[m], bv[n], acc[m][n], 0, 0, 0);
    asm volatile("s_barrier" ::: "memory");
  }
  asm volatile("s_waitcnt vmcnt(0)" ::: "memory");
  asm volatile("s_barrier" ::: "memory");
  {
    const int8_t* smr = sm + (((nkt - 1) & 1) << 14);
    i32x4_t av[4], bv[4];
#pragma unroll
    for (int i = 0; i < 4; ++i) av[i] = *(const i32x4_t*)(smr + a_off[i]);
#pragma unroll
    for (int i = 0; i < 4; ++i) bv[i] = *(const i32x4_t*)(smr + b_off[i]);
#pragma unroll
    for (int m = 0; m < 4; ++m)
#pragma unroll
      for (int n = 0; n < 4; ++n)
        acc[m][n] = __builtin_amdgcn_mfma_i32_16x16x64_i8(av[m], bv[n], acc[m][n], 0, 0, 0);
  }

#pragma unroll
  for (int n = 0; n < 4; ++n) {
    const int oc = col0 + wcol * 64 + n * 16 + (lane & 15);
    if (oc < 10) {
      const float sc = scale[oc], of = offs[oc];
#pragma unroll
      for (int m = 0; m < 4; ++m) {
        const int orb = row0 + wrow * 64 + m * 16 + ((lane >> 4) << 2);
#pragma unroll
        for (int r = 0; r < 4; ++r)
          out[(size_t)(orb + r) * 10 + oc] = sc * (float)acc[m][n][r] + of;
      }
    }
  }
}

// ===================== FALLBACK PATH (round-1 popcount) =====================

#define A0_STRIDE 28

__global__ __launch_bounds__(256) void pack_w_kernel(
    const float* __restrict__ W, uint32_t* __restrict__ Wp,
    int nout, int K, int wstride) {
  int idx = blockIdx.x * blockDim.x + threadIdx.x;
  if (idx >= nout * wstride) return;
  int n = idx / wstride;
  int wi = idx - n * wstride;
  const float* wr = W + (size_t)n * K;
  uint32_t word = 0;
  int base = wi * 32;
  for (int i = 0; i < 32; ++i) {
    int c = base + i;
    if (c < K && wr[c] > 0.f) word |= (1u << i);
  }
  Wp[idx] = word;
}

__global__ __launch_bounds__(256) void prep_thr_kernel(
    const float* __restrict__ b, const float* __restrict__ gamma,
    const float* __restrict__ beta, const float* __restrict__ mean,
    const float* __restrict__ var, int K, int N,
    int* __restrict__ thr, uint32_t* __restrict__ flipm) {
  int n = blockIdx.x * blockDim.x + threadIdx.x;
  if (n >= N) return;
  double g = (double)gamma[n];
  double rs = 1.0 / sqrt((double)var[n] + 1e-5);
  int th;
  if (g != 0.0) {
    double t = (double)mean[n] - (double)b[n] - (double)beta[n] / (g * rs);
    double pt = ((double)K - t) * 0.5;
    th = (g > 0.0) ? (int)ceil(pt) : ((int)floor(pt) + 1);
  } else {
    th = (beta[n] > 0.f) ? (K + 2) : -1;
  }
  thr[n] = th;
  if ((n & 31) == 0) {
    uint32_t m = 0;
    for (int i = 0; i < 32 && (n + i) < N; ++i)
      if (gamma[n + i] < 0.f) m |= (1u << i);
    flipm[n >> 5] = m;
  }
}

__global__ __launch_bounds__(64) void prep_out_kernel(
    const float* __restrict__ b, const float* __restrict__ gamma,
    const float* __restrict__ beta, const float* __restrict__ mean,
    const float* __restrict__ var, int N,
    float* __restrict__ s, float* __restrict__ o) {
  int n = threadIdx.x;
  if (n >= N) return;
  double rs = 1.0 / sqrt((double)var[n] + 1e-5);
  double sd = (double)gamma[n] * rs;
  s[n] = (float)sd;
  o[n] = (float)(sd * ((double)b[n] - (double)mean[n]) + (double)beta[n]);
}

__global__ __launch_bounds__(256) void pack_a_kernel(
    const float* __restrict__ x, uint32_t* __restrict__ A0) {
  int gt = blockIdx.x * blockDim.x + threadIdx.x;
  int wv = gt >> 6;
  int lane = gt & 63;
  int row = wv / 13;
  int seg = wv - row * 13;
  int col = (seg << 6) + lane;
  bool pred = (col < 784) && (x[(size_t)row * 784 + col] > 0.f);
  unsigned long long m = __ballot(pred);
  int widx = seg * 2;
  if (lane == 0)
    A0[(size_t)row * A0_STRIDE + widx] = (uint32_t)m;
  else if (lane == 1 && widx + 1 < 25)
    A0[(size_t)row * A0_STRIDE + widx + 1] = (uint32_t)(m >> 32);
}

__device__ __forceinline__ void layer1024(
    uint32_t a[32], const uint32_t* __restrict__ Wp,
    const int* __restrict__ thr, const uint32_t* __restrict__ fm,
    uint32_t* lds, int lane, int w) {
  const int nb = w * 128;
  uint32_t word = 0;
#pragma unroll 2
  for (int ni = 0; ni < 128; ++ni) {
    const int n = nb + ni;
    const uint32_t* __restrict__ wp = Wp + n * 32;
    uint32_t p0 = 0, p1 = 0, p2 = 0, p3 = 0;
#pragma unroll
    for (int k = 0; k < 32; k += 4) {
      p0 += __popc(a[k + 0] ^ wp[k + 0]);
      p1 += __popc(a[k + 1] ^ wp[k + 1]);
      p2 += __popc(a[k + 2] ^ wp[k + 2]);
      p3 += __popc(a[k + 3] ^ wp[k + 3]);
    }
    int p = (int)(p0 + p1 + p2 + p3);
    word |= ((p < thr[n]) ? 1u : 0u) << (ni & 31);
    if ((ni & 31) == 31) {
      lds[lane * 33 + (n >> 5)] = word ^ fm[n >> 5];
      word = 0;
    }
  }
  __syncthreads();
#pragma unroll
  for (int k = 0; k < 32; ++k) a[k] = lds[lane * 33 + k];
  __syncthreads();
}

__global__ __launch_bounds__(512, 4) void fused_kernel(
    const uint32_t* __restrict__ A0,
    const uint32_t* __restrict__ Wp1, const int* __restrict__ thr1, const uint32_t* __restrict__ fm1,
    const uint32_t* __restrict__ Wp2, const int* __restrict__ thr2, const uint32_t* __restrict__ fm2,
    const uint32_t* __restrict__ Wp3, const int* __restrict__ thr3, const uint32_t* __restrict__ fm3,
    const uint32_t* __restrict__ Wp4, const float* __restrict__ s4, const float* __restrict__ o4,
    float* __restrict__ out) {
  __shared__ uint32_t lds[64 * 33];
  const int lane = threadIdx.x & 63;
  const int w = __builtin_amdgcn_readfirstlane((int)(threadIdx.x >> 6));
  const int row = blockIdx.x * 64 + lane;

  uint32_t a[32];
  {
    const uint4* A4 = (const uint4*)(A0 + (size_t)row * A0_STRIDE);
#pragma unroll
    for (int i = 0; i < 7; ++i) {
      uint4 q = A4[i];
      a[4 * i + 0] = q.x; a[4 * i + 1] = q.y; a[4 * i + 2] = q.z; a[4 * i + 3] = q.w;
    }
  }
  {
    const int nb = w * 128;
    uint32_t word = 0;
#pragma unroll 2
    for (int ni = 0; ni < 128; ++ni) {
      const int n = nb + ni;
      const uint32_t* __restrict__ wp = Wp1 + n * A0_STRIDE;
      uint32_t p0 = 0, p1 = 0, p2 = 0, p3 = 0;
#pragma unroll
      for (int k = 0; k < 24; k += 4) {
        p0 += __popc(a[k + 0] ^ wp[k + 0]);
        p1 += __popc(a[k + 1] ^ wp[k + 1]);
        p2 += __popc(a[k + 2] ^ wp[k + 2]);
        p3 += __popc(a[k + 3] ^ wp[k + 3]);
      }
      p0 += __popc(a[24] ^ wp[24]);
      int p = (int)(p0 + p1 + p2 + p3);
      word |= ((p < thr1[n]) ? 1u : 0u) << (ni & 31);
      if ((ni & 31) == 31) {
        lds[lane * 33 + (n >> 5)] = word ^ fm1[n >> 5];
        word = 0;
      }
    }
    __syncthreads();
#pragma unroll
    for (int k = 0; k < 32; ++k) a[k] = lds[lane * 33 + k];
    __syncthreads();
  }
  layer1024(a, Wp2, thr2, fm2, lds, lane, w);
  layer1024(a, Wp3, thr3, fm3, lds, lane, w);
  for (int j = w; j < 10; j += 8) {
    const uint32_t* __restrict__ wp = Wp4 + j * 32;
    uint32_t p0 = 0, p1 = 0, p2 = 0, p3 = 0;
#pragma unroll
    for (int k = 0; k < 32; k += 4) {
      p0 += __popc(a[k + 0] ^ wp[k + 0]);
      p1 += __popc(a[k + 1] ^ wp[k + 1]);
      p2 += __popc(a[k + 2] ^ wp[k + 2]);
      p3 += __popc(a[k + 3] ^ wp[k + 3]);
    }
    float dotf = 1024.f - 2.f * (float)(p0 + p1 + p2 + p3);
    out[(size_t)row * 10 + j] = s4[j] * dotf + o4[j];
  }
}

// ---------------------------------------------------------------------------
extern "C" void kernel_launch(void* const* d_in, const int* in_sizes, int n_in,
                              void* d_out, int out_size, void* d_ws, size_t ws_size,
                              hipStream_t stream) {
  const float* x   = (const float*)d_in[0];
  const float* W1  = (const float*)d_in[1];
  const float* b1  = (const float*)d_in[2];
  const float* g1  = (const float*)d_in[3];
  const float* be1 = (const float*)d_in[4];
  const float* m1  = (const float*)d_in[5];
  const float* v1  = (const float*)d_in[6];
  const float* W2  = (const float*)d_in[7];
  const float* b2  = (const float*)d_in[8];
  const float* g2  = (const float*)d_in[9];
  const float* be2 = (const float*)d_in[10];
  const float* m2  = (const float*)d_in[11];
  const float* v2  = (const float*)d_in[12];
  const float* W3  = (const float*)d_in[13];
  const float* b3  = (const float*)d_in[14];
  const float* g3  = (const float*)d_in[15];
  const float* be3 = (const float*)d_in[16];
  const float* m3  = (const float*)d_in[17];
  const float* v3  = (const float*)d_in[18];
  const float* W4  = (const float*)d_in[19];
  const float* b4  = (const float*)d_in[20];
  const float* g4  = (const float*)d_in[21];
  const float* be4 = (const float*)d_in[22];
  const float* m4  = (const float*)d_in[23];
  const float* v4  = (const float*)d_in[24];
  float* outp = (float*)d_out;
  (void)in_sizes; (void)n_in; (void)out_size;

  uint8_t* ws = (uint8_t*)d_ws;
  const size_t NEED = 100ULL << 20;

  if (ws_size >= NEED) {
    size_t off = 0;
    int8_t* A0  = (int8_t*)(ws + off); off += (size_t)32768 * 832;
    int8_t* Bp1 = (int8_t*)(ws + off); off += (size_t)32768 * 1024;
    int8_t* Bp2 = (int8_t*)(ws + off); off += (size_t)32768 * 1024;
    int8_t* Wp1 = (int8_t*)(ws + off); off += (size_t)1024 * 832;
    int8_t* Wp2 = (int8_t*)(ws + off); off += (size_t)1024 * 1024;
    int8_t* Wp3 = (int8_t*)(ws + off); off += (size_t)1024 * 1024;
    int8_t* Wp4 = (int8_t*)(ws + off); off += (size_t)128 * 1024;
    int* T1     = (int*)(ws + off);    off += 4096;
    int* T2     = (int*)(ws + off);    off += 4096;
    int* T3     = (int*)(ws + off);    off += 4096;
    int8_t* S1  = (int8_t*)(ws + off); off += 1024;
    int8_t* S2  = (int8_t*)(ws + off); off += 1024;
    int8_t* S3  = (int8_t*)(ws + off); off += 1024;
    float* sc4  = (float*)(ws + off);  off += 512;
    float* of4  = (float*)(ws + off);  off += 512;

    prep_mega_kernel<<<35981, 256, 0, stream>>>(
        x, A0, W1, W2, W3, W4, Wp1, Wp2, Wp3, Wp4,
        b1, g1, be1, m1, v1, b2, g2, be2, m2, v2,
        b3, g3, be3, m3, v3, b4, g4, be4, m4, v4,
        T1, T2, T3, S1, S2, S3, sc4, of4);

    gemm_bnn256p_kernel<<<512, 512, 0, stream>>>(A0, Wp1, 832, 13, T1, S1, Bp1);
    gemm_bnn256p_kernel<<<512, 512, 0, stream>>>(Bp1, Wp2, 1024, 16, T2, S2, Bp2);
    gemm_bnn256p_kernel<<<512, 512, 0, stream>>>(Bp2, Wp3, 1024, 16, T3, S3, Bp1);
    gemm_final_kernel<<<256, 256, 0, stream>>>(Bp1, Wp4, 1024, 16, sc4, of4, outp);
  } else {
    size_t off = 0;
    uint32_t* A0  = (uint32_t*)(ws + off); off += (size_t)32768 * A0_STRIDE * 4;
    uint32_t* Wp1 = (uint32_t*)(ws + off); off += (size_t)1024 * A0_STRIDE * 4;
    uint32_t* Wp2 = (uint32_t*)(ws + off); off += (size_t)1024 * 32 * 4;
    uint32_t* Wp3 = (uint32_t*)(ws + off); off += (size_t)1024 * 32 * 4;
    uint32_t* Wp4 = (uint32_t*)(ws + off); off += 4096;
    int* thr1     = (int*)(ws + off);      off += 4096;
    int* thr2     = (int*)(ws + off);      off += 4096;
    int* thr3     = (int*)(ws + off);      off += 4096;
    uint32_t* fm1 = (uint32_t*)(ws + off); off += 128;
    uint32_t* fm2 = (uint32_t*)(ws + off); off += 128;
    uint32_t* fm3 = (uint32_t*)(ws + off); off += 128;
    float* s4o    = (float*)(ws + off);    off += 64;
    float* o4o    = (float*)(ws + off);    off += 64;

    pack_w_kernel<<<(1024 * A0_STRIDE + 255) / 256, 256, 0, stream>>>(W1, Wp1, 1024, 784, A0_STRIDE);
    pack_w_kernel<<<(1024 * 32 + 255) / 256, 256, 0, stream>>>(W2, Wp2, 1024, 1024, 32);
    pack_w_kernel<<<(1024 * 32 + 255) / 256, 256, 0, stream>>>(W3, Wp3, 1024, 1024, 32);
    pack_w_kernel<<<(10 * 32 + 255) / 256, 256, 0, stream>>>(W4, Wp4, 10, 1024, 32);
    prep_thr_kernel<<<4, 256, 0, stream>>>(b1, g1, be1, m1, v1, 784, 1024, thr1, fm1);
    prep_thr_kernel<<<4, 256, 0, stream>>>(b2, g2, be2, m2, v2, 1024, 1024, thr2, fm2);
    prep_thr_kernel<<<4, 256, 0, stream>>>(b3, g3, be3, m3, v3, 1024, 1024, thr3, fm3);
    prep_out_kernel<<<1, 64, 0, stream>>>(b4, g4, be4, m4, v4, 10, s4o, o4o);
    pack_a_kernel<<<(32768 * 13) / 4, 256, 0, stream>>>(x, A0);
    fused_kernel<<<512, 512, 0, stream>>>(A0, Wp1, thr1, fm1, Wp2, thr2, fm2,
                                          Wp3, thr3, fm3, Wp4, s4o, o4o, outp);
  }
}

// Round 9
// 308.529 us; speedup vs baseline: 1.0449x; 1.0449x over previous
//
#include <hip/hip_runtime.h>
#include <cstdint>
#include <climits>

// Binarized 4-layer MLP via exact int8 MFMA (i32 accum) on gfx950.
// Layers 1-3: BN+hardtanh+sign folds to an exact integer threshold on the
// i32 dot; layer 4 is affine. Round-8 (resubmit; round 8 hit an infra
// acquisition timeout): B-operand bypasses LDS entirely — prep pre-arranges
// W in MFMA B-fragment order (1 KB chunk per [kt][cb]); waves
// global_load_dwordx4 B-frags from L2 into reg double-buffer. LDS holds
// only A (16 KB dbuf). Rationale: rounds 4-7 were LDS-port-bound (96 KB
// reads + 32 KB writes per tile ~= MFMA time), schedule-invariant.

typedef __attribute__((ext_vector_type(4))) int i32x4_t;

__device__ __forceinline__ void gload_lds16(const void* g, void* l) {
  __builtin_amdgcn_global_load_lds(
      (const __attribute__((address_space(1))) unsigned int*)g,
      (__attribute__((address_space(3))) unsigned int*)l, 16, 0, 0);
}

__device__ __forceinline__ int pack4(const float4 v) {
  int b0 = v.x > 0.f ? 1 : (v.x < 0.f ? -1 : 0);
  int b1 = v.y > 0.f ? 1 : (v.y < 0.f ? -1 : 0);
  int b2 = v.z > 0.f ? 1 : (v.z < 0.f ? -1 : 0);
  int b3 = v.w > 0.f ? 1 : (v.w < 0.f ? -1 : 0);
  return (b0 & 0xff) | ((b1 & 0xff) << 8) | ((b2 & 0xff) << 16) | (b3 << 24);
}

// ============================ FAST PATH (i8 MFMA) ===========================

// One dispatch: all conversions + threshold prep.
//   [0, 32768):         x rows -> i8 A0 (stride 832, pad zeroed)
//   [32768, 33600):     W1 -> Wf1 (B-frag order, nkt=13)
//   [33600, 34624):     W2 -> Wf2 (nkt=16)
//   [34624, 35648):     W3 -> Wf3 (nkt=16)
//   [35648, 35776):     W4 -> Wp4 (row-major i8, 128x1024, rows>=10 zero)
//   [35776, 35789):     thresholds (f64) + final affine params
// Wf layout: chunk c = kt*64 + cb is 1024 B; byte (l6, j) (l6=0..63, j=0..15)
//   = sign(W[cb*16 + (l6&15)][kt*64 + (l6>>4)*16 + j]), 0 beyond K.
__global__ __launch_bounds__(256) void prep_mega_kernel(
    const float* __restrict__ x, int8_t* __restrict__ A0,
    const float* __restrict__ W1f, const float* __restrict__ W2f,
    const float* __restrict__ W3f, const float* __restrict__ W4f,
    int8_t* __restrict__ Wf1, int8_t* __restrict__ Wf2,
    int8_t* __restrict__ Wf3, int8_t* __restrict__ Wp4,
    const float* b1, const float* g1, const float* be1, const float* m1, const float* v1,
    const float* b2, const float* g2, const float* be2, const float* m2, const float* v2,
    const float* b3, const float* g3, const float* be3, const float* m3, const float* v3,
    const float* b4, const float* g4, const float* be4, const float* m4, const float* v4,
    int* __restrict__ T1, int* __restrict__ T2, int* __restrict__ T3,
    int8_t* __restrict__ S1, int8_t* __restrict__ S2, int8_t* __restrict__ S3,
    float* __restrict__ sc4, float* __restrict__ of4) {
  const int b = blockIdx.x;
  const int t = threadIdx.x;
  if (b < 32768) {
    const int col = t * 4;
    if (col < 784) {
      int packed = pack4(*(const float4*)(x + (size_t)b * 784 + col));
      *(int*)(A0 + (size_t)b * 832 + col) = packed;
    } else if (col < 832) {
      *(int*)(A0 + (size_t)b * 832 + col) = 0;  // zero the K-pad
    }
  } else if (b < 35648) {
    // B-fragment-order weight conversion
    const int b2i = b - 32768;
    const float* Wf; int8_t* Wo; int Kreal, blk;
    if (b2i < 832)        { Wf = W1f; Wo = Wf1; Kreal = 784;  blk = b2i;        }
    else if (b2i < 1856)  { Wf = W2f; Wo = Wf2; Kreal = 1024; blk = b2i - 832;  }
    else                  { Wf = W3f; Wo = Wf3; Kreal = 1024; blk = b2i - 1856; }
    const int o = (blk * 256 + t) * 4;
    const int j  = o & 15;
    const int l6 = (o >> 4) & 63;
    const int cb = (o >> 10) & 63;
    const int kt = o >> 16;
    const int colw = cb * 16 + (l6 & 15);
    const int k = kt * 64 + ((l6 >> 4) << 4) + j;
    int packed = 0;
    if (k < Kreal)  // k%4==0 and Kreal%4==0 -> no straddle
      packed = pack4(*(const float4*)(Wf + (size_t)colw * Kreal + k));
    *(int*)(Wo + o) = packed;
  } else if (b < 35776) {
    const int n = b - 35648;
    const int col = t * 4;
    int packed = 0;
    if (n < 10)
      packed = pack4(*(const float4*)(W4f + (size_t)n * 1024 + col));
    *(int*)(Wp4 + (size_t)n * 1024 + col) = packed;
  } else {
    const int pb = b - 35776;
    if (pb < 12) {
      const int layer = pb >> 2;
      const int n = (pb & 3) * 256 + t;
      const float *bb, *gg, *be, *me, *va; int* T; int8_t* S;
      if (layer == 0)      { bb = b1; gg = g1; be = be1; me = m1; va = v1; T = T1; S = S1; }
      else if (layer == 1) { bb = b2; gg = g2; be = be2; me = m2; va = v2; T = T2; S = S2; }
      else                 { bb = b3; gg = g3; be = be3; me = m3; va = v3; T = T3; S = S3; }
      double g = (double)gg[n];
      double rs = 1.0 / sqrt((double)va[n] + 1e-5);
      int th; int8_t s;
      if (g > 0.0) {
        double tv = (double)me[n] - (double)bb[n] - (double)be[n] / (g * rs);
        tv = fmin(fmax(tv, -2.0e9), 2.0e9);
        th = (int)floor(tv) + 1; s = 1;
      } else if (g < 0.0) {
        double tv = (double)me[n] - (double)bb[n] - (double)be[n] / (g * rs);
        tv = fmin(fmax(tv, -2.0e9), 2.0e9);
        th = (int)ceil(tv); s = -1;
      } else {
        th = INT_MIN; s = (be[n] > 0.f) ? (int8_t)1 : (int8_t)-1;
      }
      T[n] = th; S[n] = s;
    } else if (t < 10) {
      double rs = 1.0 / sqrt((double)v4[t] + 1e-5);
      double sd = (double)g4[t] * rs;
      sc4[t] = (float)sd;
      of4[t] = (float)(sd * ((double)b4[t] - (double)m4[t]) + (double)be4[t]);
    }
  }
}

// BM=128 x BN=256, BK=64, 256 threads = 4 waves (1M x 4N), wave tile 128x64
// = 8x4 frags of mfma_i32_16x16x64_i8. A via LDS (16 KB dbuf, 16B-slot XOR
// swizzle, pre-swizzled global source); B via global_load_dwordx4 from the
// pre-arranged Wf (L2-hot, 1 KB/frag), reg double-buffered (bvA/bvB, manual
// 2-unroll -> static indexing). vmcnt(6)=2 A-lds + 4 B-reg per tile, never
// drained mid-loop. __launch_bounds__(256,2) -> 2 blocks/CU. Grid 1024,
// bijective XCD swizzle: each A-stripe's 4 col-blocks on one XCD.
__global__ __launch_bounds__(256, 2) void gemm_bd_kernel(
    const int8_t* __restrict__ A, const int8_t* __restrict__ Wf,
    int ldk, int nkt,
    const int* __restrict__ T, const int8_t* __restrict__ S,
    int8_t* __restrict__ Aout) {
  __shared__ i32x4_t smem[1024];  // 16 KiB: 2 bufs x 8 KiB A-tile
  int8_t* sm = (int8_t*)smem;
  const int tid = threadIdx.x;
  const int lane = tid & 63;
  const int wn = tid >> 6;         // 0..3 (N-wave)

  // XCD swizzle: 1024 blocks = 8 XCDs x 128; per XCD 32 stripes x 4 cols
  const int bid = blockIdx.x;
  const int swz = (bid & 7) * 128 + (bid >> 3);
  const int row0 = (swz >> 2) * 128;   // 256 row stripes
  const int col0 = (swz & 3) * 256;    // 4 col blocks

  // A staging: 512 granules (16B) per tile, 2/thread; row r, slot XOR swizzle
  const int jA0 = tid, jA1 = tid + 256;
  const int rA0 = jA0 >> 2, rA1 = jA1 >> 2;
  const int sA0 = (jA0 & 3) ^ ((rA0 >> 1) & 3);
  const int sA1 = (jA1 & 3) ^ ((rA1 >> 1) & 3);
  const int8_t* aS0 = A + (size_t)(row0 + rA0) * ldk + sA0 * 16;
  const int8_t* aS1 = A + (size_t)(row0 + rA1) * ldk + sA1 * 16;
  const int dA0 = jA0 * 16, dA1 = jA1 * 16;

  // B fragment base: chunk = kt*64 + cb, cb = col0/16 + wn*4 + n
  const int8_t* const bfp =
      Wf + ((size_t)((swz & 3) * 16 + wn * 4)) * 1024 + lane * 16;

  // per-lane LDS read byte offsets (within one 8 KiB buffer)
  int a_off[8];
#pragma unroll
  for (int m = 0; m < 8; ++m) {
    int ra = m * 16 + (lane & 15);
    a_off[m] = ra * 64 + ((((lane >> 4) ^ (ra >> 1)) & 3) << 4);
  }

  i32x4_t acc[8][4];
#pragma unroll
  for (int m = 0; m < 8; ++m)
#pragma unroll
    for (int n = 0; n < 4; ++n) acc[m][n] = (i32x4_t){0, 0, 0, 0};

  // prologue: stage A tile0 -> buf0; load B tile0 -> bvA  (6 VMEM in flight)
  gload_lds16(aS0, sm + dA0);
  gload_lds16(aS1, sm + dA1);
  aS0 += 64; aS1 += 64;
  i32x4_t bvA[4], bvB[4];
#pragma unroll
  for (int n = 0; n < 4; ++n) bvA[n] = *(const i32x4_t*)(bfp + n * 1024);

#define GEMM_STEP(KT, BVC, BVN)                                               \
  {                                                                           \
    const int kt_ = (KT);                                                     \
    if (kt_ + 1 < nkt) {                                                      \
      int8_t* bufw = sm + (((kt_ + 1) & 1) << 13);                            \
      gload_lds16(aS0, bufw + dA0);                                           \
      gload_lds16(aS1, bufw + dA1);                                           \
      aS0 += 64; aS1 += 64;                                                   \
      _Pragma("unroll")                                                       \
      for (int n = 0; n < 4; ++n)                                             \
        BVN[n] = *(const i32x4_t*)(bfp + (size_t)(kt_ + 1) * 65536 + n * 1024); \
      asm volatile("s_waitcnt vmcnt(6)" ::: "memory");                        \
    } else {                                                                  \
      asm volatile("s_waitcnt vmcnt(0)" ::: "memory");                        \
    }                                                                         \
    asm volatile("s_barrier" ::: "memory");                                   \
    const int8_t* bufr = sm + ((kt_ & 1) << 13);                              \
    i32x4_t av[8];                                                            \
    _Pragma("unroll")                                                         \
    for (int i = 0; i < 8; ++i) av[i] = *(const i32x4_t*)(bufr + a_off[i]);   \
    __builtin_amdgcn_s_setprio(1);                                            \
    _Pragma("unroll")                                                         \
    for (int m = 0; m < 8; ++m)                                               \
      _Pragma("unroll")                                                       \
      for (int n = 0; n < 4; ++n)                                             \
        acc[m][n] = __builtin_amdgcn_mfma_i32_16x16x64_i8(av[m], BVC[n], acc[m][n], 0, 0, 0); \
    __builtin_amdgcn_s_setprio(0);                                            \
    asm volatile("s_barrier" ::: "memory");                                   \
  }

  int kt = 0;
  for (; kt + 2 <= nkt; kt += 2) {
    GEMM_STEP(kt, bvA, bvB);
    GEMM_STEP(kt + 1, bvB, bvA);
  }
  if (kt < nkt) GEMM_STEP(kt, bvA, bvB);  // odd-nkt tail (no further loads)
#undef GEMM_STEP

  // epilogue: C/D layout col=lane&15, row=(lane>>4)*4+reg  [verified m89]
#pragma unroll
  for (int n = 0; n < 4; ++n) {
    const int oc = col0 + wn * 64 + n * 16 + (lane & 15);
    const int tn = T[oc];
    const int8_t sn = S[oc];
#pragma unroll
    for (int m = 0; m < 8; ++m) {
      const int orb = row0 + m * 16 + ((lane >> 4) << 2);
#pragma unroll
      for (int r = 0; r < 4; ++r) {
        int8_t v = (acc[m][n][r] >= tn) ? sn : (int8_t)(-sn);
        Aout[(size_t)(orb + r) * 1024 + oc] = v;
      }
    }
  }
}

// Final layer: 128x128 tile (only cols 0..9 live), proven 2-phase structure.
__global__ __launch_bounds__(256) void gemm_final_kernel(
    const int8_t* __restrict__ A, const int8_t* __restrict__ W,
    int ldk, int nkt,
    const float* __restrict__ scale, const float* __restrict__ offs,
    float* __restrict__ out) {
  __shared__ i32x4_t smem[2048];  // 32 KiB
  int8_t* sm = (int8_t*)smem;
  const int tid = threadIdx.x;
  const int lane = tid & 63;
  const int w = tid >> 6;
  const int wrow = w >> 1, wcol = w & 1;
  const int row0 = blockIdx.x * 128;
  const int col0 = 0;

  const int jj0 = tid, jj1 = tid + 256;
  const int r0 = jj0 >> 2, r1 = jj1 >> 2;
  const int s0 = (jj0 & 3) ^ ((r0 >> 1) & 3);
  const int s1 = (jj1 & 3) ^ ((r1 >> 1) & 3);
  const int8_t* aS0 = A + (size_t)(row0 + r0) * ldk + s0 * 16;
  const int8_t* aS1 = A + (size_t)(row0 + r1) * ldk + s1 * 16;
  const int8_t* bS0 = W + (size_t)(col0 + r0) * ldk + s0 * 16;
  const int8_t* bS1 = W + (size_t)(col0 + r1) * ldk + s1 * 16;
  const int dA0 = jj0 * 16, dA1 = jj1 * 16;
  const int dB0 = 8192 + jj0 * 16, dB1 = 8192 + jj1 * 16;

  int a_off[4], b_off[4];
#pragma unroll
  for (int i = 0; i < 4; ++i) {
    int ra = wrow * 64 + i * 16 + (lane & 15);
    a_off[i] = ra * 64 + ((((lane >> 4) ^ (ra >> 1)) & 3) << 4);
    int rb = wcol * 64 + i * 16 + (lane & 15);
    b_off[i] = 8192 + rb * 64 + ((((lane >> 4) ^ (rb >> 1)) & 3) << 4);
  }

  i32x4_t acc[4][4];
#pragma unroll
  for (int m = 0; m < 4; ++m)
#pragma unroll
    for (int n = 0; n < 4; ++n) acc[m][n] = (i32x4_t){0, 0, 0, 0};

  gload_lds16(aS0, sm + dA0);
  gload_lds16(aS1, sm + dA1);
  gload_lds16(bS0, sm + dB0);
  gload_lds16(bS1, sm + dB1);

  for (int kt = 0; kt < nkt - 1; ++kt) {
    aS0 += 64; aS1 += 64; bS0 += 64; bS1 += 64;
    int8_t* smw = sm + (((kt + 1) & 1) << 14);
    gload_lds16(aS0, smw + dA0);
    gload_lds16(aS1, smw + dA1);
    gload_lds16(bS0, smw + dB0);
    gload_lds16(bS1, smw + dB1);
    asm volatile("s_waitcnt vmcnt(4)" ::: "memory");
    asm volatile("s_barrier" ::: "memory");
    const int8_t* smr = sm + ((kt & 1) << 14);
    i32x4_t av[4], bv[4];
#pragma unroll
    for (int i = 0; i < 4; ++i) av[i] = *(const i32x4_t*)(smr + a_off[i]);
#pragma unroll
    for (int i = 0; i < 4; ++i) bv[i] = *(const i32x4_t*)(smr + b_off[i]);
#pragma unroll
    for (int m = 0; m < 4; ++m)
#pragma unroll
      for (int n = 0; n < 4; ++n)
        acc[m][n] = __builtin_amdgcn_mfma_i32_16x16x64_i8(av[m], bv[n], acc[m][n], 0, 0, 0);
    asm volatile("s_barrier" ::: "memory");
  }
  asm volatile("s_waitcnt vmcnt(0)" ::: "memory");
  asm volatile("s_barrier" ::: "memory");
  {
    const int8_t* smr = sm + (((nkt - 1) & 1) << 14);
    i32x4_t av[4], bv[4];
#pragma unroll
    for (int i = 0; i < 4; ++i) av[i] = *(const i32x4_t*)(smr + a_off[i]);
#pragma unroll
    for (int i = 0; i < 4; ++i) bv[i] = *(const i32x4_t*)(smr + b_off[i]);
#pragma unroll
    for (int m = 0; m < 4; ++m)
#pragma unroll
      for (int n = 0; n < 4; ++n)
        acc[m][n] = __builtin_amdgcn_mfma_i32_16x16x64_i8(av[m], bv[n], acc[m][n], 0, 0, 0);
  }

#pragma unroll
  for (int n = 0; n < 4; ++n) {
    const int oc = col0 + wcol * 64 + n * 16 + (lane & 15);
    if (oc < 10) {
      const float sc = scale[oc], of = offs[oc];
#pragma unroll
      for (int m = 0; m < 4; ++m) {
        const int orb = row0 + wrow * 64 + m * 16 + ((lane >> 4) << 2);
#pragma unroll
        for (int r = 0; r < 4; ++r)
          out[(size_t)(orb + r) * 10 + oc] = sc * (float)acc[m][n][r] + of;
      }
    }
  }
}

// ===================== FALLBACK PATH (round-1 popcount) =====================

#define A0_STRIDE 28

__global__ __launch_bounds__(256) void pack_w_kernel(
    const float* __restrict__ W, uint32_t* __restrict__ Wp,
    int nout, int K, int wstride) {
  int idx = blockIdx.x * blockDim.x + threadIdx.x;
  if (idx >= nout * wstride) return;
  int n = idx / wstride;
  int wi = idx - n * wstride;
  const float* wr = W + (size_t)n * K;
  uint32_t word = 0;
  int base = wi * 32;
  for (int i = 0; i < 32; ++i) {
    int c = base + i;
    if (c < K && wr[c] > 0.f) word |= (1u << i);
  }
  Wp[idx] = word;
}

__global__ __launch_bounds__(256) void prep_thr_kernel(
    const float* __restrict__ b, const float* __restrict__ gamma,
    const float* __restrict__ beta, const float* __restrict__ mean,
    const float* __restrict__ var, int K, int N,
    int* __restrict__ thr, uint32_t* __restrict__ flipm) {
  int n = blockIdx.x * blockDim.x + threadIdx.x;
  if (n >= N) return;
  double g = (double)gamma[n];
  double rs = 1.0 / sqrt((double)var[n] + 1e-5);
  int th;
  if (g != 0.0) {
    double t = (double)mean[n] - (double)b[n] - (double)beta[n] / (g * rs);
    double pt = ((double)K - t) * 0.5;
    th = (g > 0.0) ? (int)ceil(pt) : ((int)floor(pt) + 1);
  } else {
    th = (beta[n] > 0.f) ? (K + 2) : -1;
  }
  thr[n] = th;
  if ((n & 31) == 0) {
    uint32_t m = 0;
    for (int i = 0; i < 32 && (n + i) < N; ++i)
      if (gamma[n + i] < 0.f) m |= (1u << i);
    flipm[n >> 5] = m;
  }
}

__global__ __launch_bounds__(64) void prep_out_kernel(
    const float* __restrict__ b, const float* __restrict__ gamma,
    const float* __restrict__ beta, const float* __restrict__ mean,
    const float* __restrict__ var, int N,
    float* __restrict__ s, float* __restrict__ o) {
  int n = threadIdx.x;
  if (n >= N) return;
  double rs = 1.0 / sqrt((double)var[n] + 1e-5);
  double sd = (double)gamma[n] * rs;
  s[n] = (float)sd;
  o[n] = (float)(sd * ((double)b[n] - (double)mean[n]) + (double)beta[n]);
}

__global__ __launch_bounds__(256) void pack_a_kernel(
    const float* __restrict__ x, uint32_t* __restrict__ A0) {
  int gt = blockIdx.x * blockDim.x + threadIdx.x;
  int wv = gt >> 6;
  int lane = gt & 63;
  int row = wv / 13;
  int seg = wv - row * 13;
  int col = (seg << 6) + lane;
  bool pred = (col < 784) && (x[(size_t)row * 784 + col] > 0.f);
  unsigned long long m = __ballot(pred);
  int widx = seg * 2;
  if (lane == 0)
    A0[(size_t)row * A0_STRIDE + widx] = (uint32_t)m;
  else if (lane == 1 && widx + 1 < 25)
    A0[(size_t)row * A0_STRIDE + widx + 1] = (uint32_t)(m >> 32);
}

__device__ __forceinline__ void layer1024(
    uint32_t a[32], const uint32_t* __restrict__ Wp,
    const int* __restrict__ thr, const uint32_t* __restrict__ fm,
    uint32_t* lds, int lane, int w) {
  const int nb = w * 128;
  uint32_t word = 0;
#pragma unroll 2
  for (int ni = 0; ni < 128; ++ni) {
    const int n = nb + ni;
    const uint32_t* __restrict__ wp = Wp + n * 32;
    uint32_t p0 = 0, p1 = 0, p2 = 0, p3 = 0;
#pragma unroll
    for (int k = 0; k < 32; k += 4) {
      p0 += __popc(a[k + 0] ^ wp[k + 0]);
      p1 += __popc(a[k + 1] ^ wp[k + 1]);
      p2 += __popc(a[k + 2] ^ wp[k + 2]);
      p3 += __popc(a[k + 3] ^ wp[k + 3]);
    }
    int p = (int)(p0 + p1 + p2 + p3);
    word |= ((p < thr[n]) ? 1u : 0u) << (ni & 31);
    if ((ni & 31) == 31) {
      lds[lane * 33 + (n >> 5)] = word ^ fm[n >> 5];
      word = 0;
    }
  }
  __syncthreads();
#pragma unroll
  for (int k = 0; k < 32; ++k) a[k] = lds[lane * 33 + k];
  __syncthreads();
}

__global__ __launch_bounds__(512, 4) void fused_kernel(
    const uint32_t* __restrict__ A0,
    const uint32_t* __restrict__ Wp1, const int* __restrict__ thr1, const uint32_t* __restrict__ fm1,
    const uint32_t* __restrict__ Wp2, const int* __restrict__ thr2, const uint32_t* __restrict__ fm2,
    const uint32_t* __restrict__ Wp3, const int* __restrict__ thr3, const uint32_t* __restrict__ fm3,
    const uint32_t* __restrict__ Wp4, const float* __restrict__ s4, const float* __restrict__ o4,
    float* __restrict__ out) {
  __shared__ uint32_t lds[64 * 33];
  const int lane = threadIdx.x & 63;
  const int w = __builtin_amdgcn_readfirstlane((int)(threadIdx.x >> 6));
  const int row = blockIdx.x * 64 + lane;

  uint32_t a[32];
  {
    const uint4* A4 = (const uint4*)(A0 + (size_t)row * A0_STRIDE);
#pragma unroll
    for (int i = 0; i < 7; ++i) {
      uint4 q = A4[i];
      a[4 * i + 0] = q.x; a[4 * i + 1] = q.y; a[4 * i + 2] = q.z; a[4 * i + 3] = q.w;
    }
  }
  {
    const int nb = w * 128;
    uint32_t word = 0;
#pragma unroll 2
    for (int ni = 0; ni < 128; ++ni) {
      const int n = nb + ni;
      const uint32_t* __restrict__ wp = Wp1 + n * A0_STRIDE;
      uint32_t p0 = 0, p1 = 0, p2 = 0, p3 = 0;
#pragma unroll
      for (int k = 0; k < 24; k += 4) {
        p0 += __popc(a[k + 0] ^ wp[k + 0]);
        p1 += __popc(a[k + 1] ^ wp[k + 1]);
        p2 += __popc(a[k + 2] ^ wp[k + 2]);
        p3 += __popc(a[k + 3] ^ wp[k + 3]);
      }
      p0 += __popc(a[24] ^ wp[24]);
      int p = (int)(p0 + p1 + p2 + p3);
      word |= ((p < thr1[n]) ? 1u : 0u) << (ni & 31);
      if ((ni & 31) == 31) {
        lds[lane * 33 + (n >> 5)] = word ^ fm1[n >> 5];
        word = 0;
      }
    }
    __syncthreads();
#pragma unroll
    for (int k = 0; k < 32; ++k) a[k] = lds[lane * 33 + k];
    __syncthreads();
  }
  layer1024(a, Wp2, thr2, fm2, lds, lane, w);
  layer1024(a, Wp3, thr3, fm3, lds, lane, w);
  for (int j = w; j < 10; j += 8) {
    const uint32_t* __restrict__ wp = Wp4 + j * 32;
    uint32_t p0 = 0, p1 = 0, p2 = 0, p3 = 0;
#pragma unroll
    for (int k = 0; k < 32; k += 4) {
      p0 += __popc(a[k + 0] ^ wp[k + 0]);
      p1 += __popc(a[k + 1] ^ wp[k + 1]);
      p2 += __popc(a[k + 2] ^ wp[k + 2]);
      p3 += __popc(a[k + 3] ^ wp[k + 3]);
    }
    float dotf = 1024.f - 2.f * (float)(p0 + p1 + p2 + p3);
    out[(size_t)row * 10 + j] = s4[j] * dotf + o4[j];
  }
}

// ---------------------------------------------------------------------------
extern "C" void kernel_launch(void* const* d_in, const int* in_sizes, int n_in,
                              void* d_out, int out_size, void* d_ws, size_t ws_size,
                              hipStream_t stream) {
  const float* x   = (const float*)d_in[0];
  const float* W1  = (const float*)d_in[1];
  const float* b1  = (const float*)d_in[2];
  const float* g1  = (const float*)d_in[3];
  const float* be1 = (const float*)d_in[4];
  const float* m1  = (const float*)d_in[5];
  const float* v1  = (const float*)d_in[6];
  const float* W2  = (const float*)d_in[7];
  const float* b2  = (const float*)d_in[8];
  const float* g2  = (const float*)d_in[9];
  const float* be2 = (const float*)d_in[10];
  const float* m2  = (const float*)d_in[11];
  const float* v2  = (const float*)d_in[12];
  const float* W3  = (const float*)d_in[13];
  const float* b3  = (const float*)d_in[14];
  const float* g3  = (const float*)d_in[15];
  const float* be3 = (const float*)d_in[16];
  const float* m3  = (const float*)d_in[17];
  const float* v3  = (const float*)d_in[18];
  const float* W4  = (const float*)d_in[19];
  const float* b4  = (const float*)d_in[20];
  const float* g4  = (const float*)d_in[21];
  const float* be4 = (const float*)d_in[22];
  const float* m4  = (const float*)d_in[23];
  const float* v4  = (const float*)d_in[24];
  float* outp = (float*)d_out;
  (void)in_sizes; (void)n_in; (void)out_size;

  uint8_t* ws = (uint8_t*)d_ws;
  const size_t NEED = 100ULL << 20;

  if (ws_size >= NEED) {
    size_t off = 0;
    int8_t* A0  = (int8_t*)(ws + off); off += (size_t)32768 * 832;
    int8_t* Bp1 = (int8_t*)(ws + off); off += (size_t)32768 * 1024;
    int8_t* Bp2 = (int8_t*)(ws + off); off += (size_t)32768 * 1024;
    int8_t* Wf1 = (int8_t*)(ws + off); off += (size_t)13 * 64 * 1024;   // 832 KB
    int8_t* Wf2 = (int8_t*)(ws + off); off += (size_t)16 * 64 * 1024;   // 1 MB
    int8_t* Wf3 = (int8_t*)(ws + off); off += (size_t)16 * 64 * 1024;   // 1 MB
    int8_t* Wp4 = (int8_t*)(ws + off); off += (size_t)128 * 1024;
    int* T1     = (int*)(ws + off);    off += 4096;
    int* T2     = (int*)(ws + off);    off += 4096;
    int* T3     = (int*)(ws + off);    off += 4096;
    int8_t* S1  = (int8_t*)(ws + off); off += 1024;
    int8_t* S2  = (int8_t*)(ws + off); off += 1024;
    int8_t* S3  = (int8_t*)(ws + off); off += 1024;
    float* sc4  = (float*)(ws + off);  off += 512;
    float* of4  = (float*)(ws + off);  off += 512;

    prep_mega_kernel<<<35789, 256, 0, stream>>>(
        x, A0, W1, W2, W3, W4, Wf1, Wf2, Wf3, Wp4,
        b1, g1, be1, m1, v1, b2, g2, be2, m2, v2,
        b3, g3, be3, m3, v3, b4, g4, be4, m4, v4,
        T1, T2, T3, S1, S2, S3, sc4, of4);

    gemm_bd_kernel<<<1024, 256, 0, stream>>>(A0, Wf1, 832, 13, T1, S1, Bp1);
    gemm_bd_kernel<<<1024, 256, 0, stream>>>(Bp1, Wf2, 1024, 16, T2, S2, Bp2);
    gemm_bd_kernel<<<1024, 256, 0, stream>>>(Bp2, Wf3, 1024, 16, T3, S3, Bp1);
    gemm_final_kernel<<<256, 256, 0, stream>>>(Bp1, Wp4, 1024, 16, sc4, of4, outp);
  } else {
    size_t off = 0;
    uint32_t* A0  = (uint32_t*)(ws + off); off += (size_t)32768 * A0_STRIDE * 4;
    uint32_t* Wp1 = (uint32_t*)(ws + off); off += (size_t)1024 * A0_STRIDE * 4;
    uint32_t* Wp2 = (uint32_t*)(ws + off); off += (size_t)1024 * 32 * 4;
    uint32_t* Wp3 = (uint32_t*)(ws + off); off += (size_t)1024 * 32 * 4;
    uint32_t* Wp4 = (uint32_t*)(ws + off); off += 4096;
    int* thr1     = (int*)(ws + off);      off += 4096;
    int* thr2     = (int*)(ws + off);      off += 4096;
    int* thr3     = (int*)(ws + off);      off += 4096;
    uint32_t* fm1 = (uint32_t*)(ws + off); off += 128;
    uint32_t* fm2 = (uint32_t*)(ws + off); off += 128;
    uint32_t* fm3 = (uint32_t*)(ws + off); off += 128;
    float* s4o    = (float*)(ws + off);    off += 64;
    float* o4o    = (float*)(ws + off);    off += 64;

    pack_w_kernel<<<(1024 * A0_STRIDE + 255) / 256, 256, 0, stream>>>(W1, Wp1, 1024, 784, A0_STRIDE);
    pack_w_kernel<<<(1024 * 32 + 255) / 256, 256, 0, stream>>>(W2, Wp2, 1024, 1024, 32);
    pack_w_kernel<<<(1024 * 32 + 255) / 256, 256, 0, stream>>>(W3, Wp3, 1024, 1024, 32);
    pack_w_kernel<<<(10 * 32 + 255) / 256, 256, 0, stream>>>(W4, Wp4, 10, 1024, 32);
    prep_thr_kernel<<<4, 256, 0, stream>>>(b1, g1, be1, m1, v1, 784, 1024, thr1, fm1);
    prep_thr_kernel<<<4, 256, 0, stream>>>(b2, g2, be2, m2, v2, 1024, 1024, thr2, fm2);
    prep_thr_kernel<<<4, 256, 0, stream>>>(b3, g3, be3, m3, v3, 1024, 1024, thr3, fm3);
    prep_out_kernel<<<1, 64, 0, stream>>>(b4, g4, be4, m4, v4, 10, s4o, o4o);
    pack_a_kernel<<<(32768 * 13) / 4, 256, 0, stream>>>(x, A0);
    fused_kernel<<<512, 512, 0, stream>>>(A0, Wp1, thr1, fm1, Wp2, thr2, fm2,
                                          Wp3, thr3, fm3, Wp4, s4o, o4o, outp);
  }
}